// Round 1
// 123.541 us; speedup vs baseline: 1.0677x; 1.0677x over previous
//
#include <hip/hip_runtime.h>

#define BB 256
#define TT 256
#define CC 256
#define HH 64

typedef _Float16 half8 __attribute__((ext_vector_type(8)));
typedef _Float16 half4 __attribute__((ext_vector_type(4)));
typedef __fp16 fp16x2 __attribute__((ext_vector_type(2)));
typedef float floatx4 __attribute__((ext_vector_type(4)));

// ---------------------------------------------------------------------------
// prep: blocks 0..63   -> rpeh[i] = (f16) rpe[i]  (rows 0..255)
//       blocks 64..255 -> WT[(w*64+n)][k] = (f16) W_w[k][n]
// ---------------------------------------------------------------------------
__global__ __launch_bounds__(256) void prep(
    const float* __restrict__ rpe,
    const float* __restrict__ Wk, const float* __restrict__ Wq, const float* __restrict__ Wv,
    _Float16* __restrict__ rpeh, _Float16* __restrict__ WT)
{
    const int bid = blockIdx.x, tid = threadIdx.x;
    if (bid < 64) {
        const int i = bid * 256 + tid;
        rpeh[i] = (_Float16)rpe[i];
    } else {
        const int wsel = (bid - 64) >> 6;          // 0=k, 1=q, 2=v
        const int n    = (bid - 64) & 63;
        const float* W = wsel == 0 ? Wk : (wsel == 1 ? Wq : Wv);
        WT[(size_t)(wsel * 64 + n) * 256 + tid] = (_Float16)W[tid * HH + n];
    }
}

// per-tile exp-weight slot pool: pair j = t>>1 shares width V_j
__device__ __forceinline__ int slot_width(int t) {
    const int j = t >> 1;
    return (j < 2) ? 72 : (32 * j + 40);
}
__device__ __forceinline__ int slot_off(int t) {      // halves, rel. to pool
    const int j = t >> 1;
    const int V = (j < 2) ? 72 : (32 * j + 40);
    const int S = (j == 0) ? 0 : (j == 1) ? 72 : (16 * j * j + 24 * j + 32);
    return 32 * S + (t & 1) * 16 * V;
}

// ---------------------------------------------------------------------------
// fused r16: one block per batch, 1024 thr (16 waves), 1 block/CU.
// r15 post-mortem: Occupancy 26.7% == triangle-drain average (wave w owned
// tile w; wave 15's 96-MFMA serial chain ran with the CU otherwise empty).
// Here phase 2 is cross-wave balanced via (t, 15-t) pairing:
//   scores: wave w does own tile s~/j in [0,min(w,8)] + partner 15-w's [9,15-w]
//           (8-9 tiles each; partner q read from partner slot before scatter)
//   sums:   <=2 writers/tile -> rowsumP[2][256], no atomics
//   PV:     64 (t,ht) tiles paired -> exactly 18 MFMA per wave
// Slot pool / K / VT layouts unchanged; +4 barriers, +2KB LDS.
// ---------------------------------------------------------------------------
__global__ __launch_bounds__(1024, 4) void fused(
    const float* __restrict__ x, const _Float16* __restrict__ WT,
    const _Float16* __restrict__ rpeh, float* __restrict__ out)
{
    __shared__ _Float16 lds[75264];        // 147 KB: K | VT | pool
    __shared__ float rowsumP[2][256];      // 2-slot row-sum partials
    _Float16* Klds = lds;                  // [256][72]
    _Float16* VT   = lds + 18432;          // [64][264]
    _Float16* pool = lds + 35328;          // 39936 halves (W chunks / slots)

    const int tid  = threadIdx.x;
    const int b    = blockIdx.x;
    const int w    = tid >> 6;
    const int lane = tid & 63;
    const int quad = lane >> 4;
    const int l    = lane & 15;

    union H8 { half8 v; fp16x2 p[4]; };
    const float4* xg = reinterpret_cast<const float4*>(x);
    const int row0g = b * 256 + w * 16;    // wave's 16 x-rows

    floatx4 acc[12];
#pragma unroll
    for (int nt = 0; nt < 12; ++nt) acc[nt] = (floatx4){0.f, 0.f, 0.f, 0.f};

    // ---- phase 1: proj in 2 K-chunks of 128 ------------------------------
#pragma unroll
    for (int c = 0; c < 2; ++c) {
        // stage W chunk c: [192][136] (3072 granules / 1024 thr = 3 each)
#pragma unroll
        for (int i = 0; i < 3; ++i) {
            const int gi  = tid + i * 1024;
            const int row = gi >> 4;
            const int g   = gi & 15;
            *(half8*)&pool[row * 136 + g * 8] =
                *(const half8*)(WT + (size_t)row * 256 + c * 128 + g * 8);
        }
        __syncthreads();

        // prefetch all 8 x float4 for this chunk (MLP), then cvt+MFMA
        float4 xa[4][2];
#pragma unroll
        for (int kk = 0; kk < 4; ++kk) {
            const size_t base = (size_t)(row0g + l) * 64 + c * 32 + kk * 8 + quad * 2;
            xa[kk][0] = xg[base];
            xa[kk][1] = xg[base + 1];
        }
#pragma unroll
        for (int kk = 0; kk < 4; ++kk) {
            H8 u;
            u.p[0] = __builtin_amdgcn_cvt_pkrtz(xa[kk][0].x, xa[kk][0].y);
            u.p[1] = __builtin_amdgcn_cvt_pkrtz(xa[kk][0].z, xa[kk][0].w);
            u.p[2] = __builtin_amdgcn_cvt_pkrtz(xa[kk][1].x, xa[kk][1].y);
            u.p[3] = __builtin_amdgcn_cvt_pkrtz(xa[kk][1].z, xa[kk][1].w);
#pragma unroll
            for (int nt = 0; nt < 12; ++nt) {
                const half8 bf = *(const half8*)&pool[(nt * 16 + l) * 136 + kk * 32 + quad * 8];
                acc[nt] = __builtin_amdgcn_mfma_f32_16x16x32_f16(u.v, bf, acc[nt], 0, 0, 0);
            }
        }
        __syncthreads();   // chunk readers done (protects restage / slots)
    }

    // ---- epilogue: K (scaled) and VT into LDS ----------------------------
    {
        const int trw = w * 16;
#pragma unroll
        for (int nt = 0; nt < 4; ++nt) {
#pragma unroll
            for (int r = 0; r < 4; ++r)
                Klds[(trw + quad * 4 + r) * 72 + nt * 16 + l] = (_Float16)(acc[nt][r] * 0.125f);
            half4 vv;
            vv[0] = (_Float16)acc[nt + 8][0];
            vv[1] = (_Float16)acc[nt + 8][1];
            vv[2] = (_Float16)acc[nt + 8][2];
            vv[3] = (_Float16)acc[nt + 8][3];
            *(half4*)&VT[(nt * 16 + l) * 264 + trw + quad * 4] = vv;
        }
    }
    if (tid < 512) ((float*)rowsumP)[tid] = 0.f;
    __syncthreads();       // B1: K/VT visible; pool free for slots

    // ---- phase 2a: q transpose into own slot -----------------------------
    _Float16* wh = pool + slot_off(w);
    const int Vw = slot_width(w);
#pragma unroll
    for (int nt = 0; nt < 4; ++nt)
#pragma unroll
        for (int r = 0; r < 4; ++r)
            wh[(quad * 4 + r) * Vw + nt * 16 + l] = (_Float16)acc[nt + 4][r];
    __syncthreads();       // B2: all q slots written

    // read q A-frags: own + partner (partner slot q-region not yet clobbered)
    const half8 qf0 = *(const half8*)&wh[l * Vw + quad * 8];
    const half8 qf1 = *(const half8*)&wh[l * Vw + 32 + quad * 8];
    const int tp = 15 - w;
    _Float16* whp = pool + slot_off(tp);
    const int Vp = slot_width(tp);
    half8 qg0 = qf0, qg1 = qf1;
    if (w < 8) {
        qg0 = *(const half8*)&whp[l * Vp + quad * 8];
        qg1 = *(const half8*)&whp[l * Vp + 32 + quad * 8];
    }
    __syncthreads();       // B3: q consumed everywhere; slots writable

    // ---- phase 2b: pos scores (skewed scatter), balanced -----------------
    const int jmaxo = (w < 8) ? w : 8;     // own bands j=0..jmaxo
#pragma unroll
    for (int j = 0; j < 9; ++j) {
        if (j <= jmaxo) {
            const int dt = j + 15 - w;
            const _Float16* rp = rpeh + (size_t)(dt * 16 + l) * HH + quad * 8;
            const half8 bf0 = *(const half8*)rp;
            const half8 bf1 = *(const half8*)(rp + 32);
            floatx4 z = {0.f, 0.f, 0.f, 0.f};
            z = __builtin_amdgcn_mfma_f32_16x16x32_f16(qf0, bf0, z, 0, 0, 0);
            const floatx4 pacc = __builtin_amdgcn_mfma_f32_16x16x32_f16(qf1, bf1, z, 0, 0, 0);
            if (j == 0) {
#pragma unroll
                for (int r = 0; r < 4; ++r) {
                    const int row = quad * 4 + r;
                    const int s   = l + row - 15;
                    if (s >= 0) wh[row * Vw + s] = (_Float16)pacc[r];
                }
            } else {
#pragma unroll
                for (int r = 0; r < 4; ++r) {
                    const int row = quad * 4 + r;
                    wh[row * Vw + 16 * j + l + row - 15] = (_Float16)pacc[r];
                }
            }
        }
    }
    if (w < 8) {                            // partner bands j=9..15-w (s>=129)
#pragma unroll
        for (int j = 9; j < 16; ++j) {
            if (j <= 15 - w) {
                const int dt = j + w;
                const _Float16* rp = rpeh + (size_t)(dt * 16 + l) * HH + quad * 8;
                const half8 bf0 = *(const half8*)rp;
                const half8 bf1 = *(const half8*)(rp + 32);
                floatx4 z = {0.f, 0.f, 0.f, 0.f};
                z = __builtin_amdgcn_mfma_f32_16x16x32_f16(qg0, bf0, z, 0, 0, 0);
                const floatx4 pacc = __builtin_amdgcn_mfma_f32_16x16x32_f16(qg1, bf1, z, 0, 0, 0);
#pragma unroll
                for (int r = 0; r < 4; ++r) {
                    const int row = quad * 4 + r;
                    whp[row * Vp + 16 * j + l + row - 15] = (_Float16)pacc[r];
                }
            }
        }
    }
    __syncthreads();       // B4: all pos bands written

    // ---- phase 2c: content scores + exp + partial row-sums ---------------
    {
        float sumsA[4] = {0.f, 0.f, 0.f, 0.f};
#pragma unroll
        for (int st = 0; st < 9; ++st) {
            if (st <= jmaxo) {
                const _Float16* kp = &Klds[(st * 16 + l) * 72 + quad * 8];
                const half8 kf0 = *(const half8*)kp;
                const half8 kf1 = *(const half8*)(kp + 32);
                floatx4 z = {0.f, 0.f, 0.f, 0.f};
                z = __builtin_amdgcn_mfma_f32_16x16x32_f16(qf0, kf0, z, 0, 0, 0);
                const floatx4 sacc = __builtin_amdgcn_mfma_f32_16x16x32_f16(qf1, kf1, z, 0, 0, 0);
                const int s = l + 16 * st;
                if (st == w) {             // own diagonal (only w<=8)
#pragma unroll
                    for (int r = 0; r < 4; ++r) {
                        const int row = quad * 4 + r;
                        float e = 0.f;
                        if (l <= row) e = __expf(sacc[r] + (float)wh[row * Vw + s]);
                        sumsA[r] += e;
                        wh[row * Vw + s] = (_Float16)e;
                    }
                    if ((w & 1) == 0) {    // zero strip covering PV read window
                        const int s2 = l + 16 * (st + 1);
#pragma unroll
                        for (int r = 0; r < 4; ++r) wh[(quad * 4 + r) * Vw + s2] = (_Float16)0.f;
                    }
                } else {
#pragma unroll
                    for (int r = 0; r < 4; ++r) {
                        const int row = quad * 4 + r;
                        const float e = __expf(sacc[r] + (float)wh[row * Vw + s]);
                        sumsA[r] += e;
                        wh[row * Vw + s] = (_Float16)e;
                    }
                }
            }
        }
#pragma unroll
        for (int r = 0; r < 4; ++r) {
            float sv = sumsA[r];
            sv += __shfl_xor(sv, 1);
            sv += __shfl_xor(sv, 2);
            sv += __shfl_xor(sv, 4);
            sv += __shfl_xor(sv, 8);
            if (l == 0) rowsumP[0][16 * w + quad * 4 + r] = sv;
        }
    }
    if (w < 8) {                            // partner tiles st=9..15-w
        float sumsB[4] = {0.f, 0.f, 0.f, 0.f};
#pragma unroll
        for (int st = 9; st < 16; ++st) {
            if (st <= 15 - w) {
                const _Float16* kp = &Klds[(st * 16 + l) * 72 + quad * 8];
                const half8 kf0 = *(const half8*)kp;
                const half8 kf1 = *(const half8*)(kp + 32);
                floatx4 z = {0.f, 0.f, 0.f, 0.f};
                z = __builtin_amdgcn_mfma_f32_16x16x32_f16(qg0, kf0, z, 0, 0, 0);
                const floatx4 sacc = __builtin_amdgcn_mfma_f32_16x16x32_f16(qg1, kf1, z, 0, 0, 0);
                const int s = l + 16 * st;
                if (st == tp) {            // partner diagonal
#pragma unroll
                    for (int r = 0; r < 4; ++r) {
                        const int row = quad * 4 + r;
                        float e = 0.f;
                        if (l <= row) e = __expf(sacc[r] + (float)whp[row * Vp + s]);
                        sumsB[r] += e;
                        whp[row * Vp + s] = (_Float16)e;
                    }
                    if ((tp & 1) == 0) {
                        const int s2 = l + 16 * (st + 1);
#pragma unroll
                        for (int r = 0; r < 4; ++r) whp[(quad * 4 + r) * Vp + s2] = (_Float16)0.f;
                    }
                } else {
#pragma unroll
                    for (int r = 0; r < 4; ++r) {
                        const int row = quad * 4 + r;
                        const float e = __expf(sacc[r] + (float)whp[row * Vp + s]);
                        sumsB[r] += e;
                        whp[row * Vp + s] = (_Float16)e;
                    }
                }
            }
        }
#pragma unroll
        for (int r = 0; r < 4; ++r) {
            float sv = sumsB[r];
            sv += __shfl_xor(sv, 1);
            sv += __shfl_xor(sv, 2);
            sv += __shfl_xor(sv, 4);
            sv += __shfl_xor(sv, 8);
            if (l == 0) rowsumP[1][16 * tp + quad * 4 + r] = sv;
        }
    }
    __syncthreads();       // B5: exp-weights + row-sums complete

    // ---- phase 2d: PV, paired (t1, 15-t1) x 2 head-tiles -> 18 MFMA/wave -
    {
        const int t1 = w >> 1;
        const int hb = (w & 1) << 1;
#pragma unroll
        for (int sel = 0; sel < 2; ++sel) {
            const int tt = sel ? (15 - t1) : t1;
            const _Float16* ws = pool + slot_off(tt);
            const int Vt    = slot_width(tt);
            const int cmaxt = tt >> 1;
            float inv[4];
#pragma unroll
            for (int r = 0; r < 4; ++r) {
                const int row = 16 * tt + quad * 4 + r;
                inv[r] = 1.0f / (rowsumP[0][row] + rowsumP[1][row]);
            }
            floatx4 o0 = {0.f, 0.f, 0.f, 0.f};
            floatx4 o1 = {0.f, 0.f, 0.f, 0.f};
#pragma unroll
            for (int c = 0; c < 8; ++c) {
                if (c <= cmaxt) {
                    const half8 af  = *(const half8*)&ws[l * Vt + c * 32 + quad * 8];
                    const half8 vf0 = *(const half8*)&VT[((hb + 0) * 16 + l) * 264 + c * 32 + quad * 8];
                    const half8 vf1 = *(const half8*)&VT[((hb + 1) * 16 + l) * 264 + c * 32 + quad * 8];
                    o0 = __builtin_amdgcn_mfma_f32_16x16x32_f16(af, vf0, o0, 0, 0, 0);
                    o1 = __builtin_amdgcn_mfma_f32_16x16x32_f16(af, vf1, o1, 0, 0, 0);
                }
            }
#pragma unroll
            for (int r = 0; r < 4; ++r) {
                const int t = 16 * tt + quad * 4 + r;
                out[(size_t)(b * TT + t) * HH + (hb + 0) * 16 + l] = o0[r] * inv[r];
                out[(size_t)(b * TT + t) * HH + (hb + 1) * 16 + l] = o1[r] * inv[r];
            }
        }
    }
}

extern "C" void kernel_launch(void* const* d_in, const int* in_sizes, int n_in,
                              void* d_out, int out_size, void* d_ws, size_t ws_size,
                              hipStream_t stream) {
    const float* x   = (const float*)d_in[0];
    const float* Wk  = (const float*)d_in[1];
    const float* Wq  = (const float*)d_in[2];
    const float* Wv  = (const float*)d_in[3];
    const float* rpe = (const float*)d_in[4];
    float* out = (float*)d_out;

    _Float16* rpeh = (_Float16*)d_ws;              // [256][64]
    _Float16* WT   = rpeh + 256 * HH;              // [192][256]

    prep<<<dim3(256), dim3(256), 0, stream>>>(rpe, Wk, Wq, Wv, rpeh, WT);
    fused<<<dim3(BB), dim3(1024), 0, stream>>>(x, WT, rpeh, out);
}